// Round 5
// baseline (169.809 us; speedup 1.0000x reference)
//
#include <hip/hip_runtime.h>
#include <hip/hip_bf16.h>
#include <stdint.h>

// ECG beat tokenizer: X[196608, 64] = ecg_rows[196608, 128] @ W[64,128]^T + b
// plus beat_intervals[128*128] = 128.0f appended at out + 196608*64.
//
// R5: kill ALL serial memory chains. Each wave issues its entire A working
// set (2 row-groups, 16x dwordx4 = 16 KB) upfront, stages W to LDS *under*
// that latency, then runs two straight-line MFMA+store passes. A-side
// fp32->bf16 is a single v_perm_b32 truncating pack (1 op/pair vs 5).
// 1536 blocks x 4 waves, launch_bounds(256,3): ~170 VGPR cap, no spill at
// ~115 demand, 12 waves/CU = 192 KB/CU loads in flight (need ~9 KB for BW).

#define BEAT_LEN   128
#define TOKEN_DIM  64
#define N_BATCH    128
#define N_BEATS    128
#define M_ROWS     196608              // 128*12*128 beat rows
#define RGROUPS    (M_ROWS / 16)       // 12288 row-groups of 16
#define WPB        4                   // waves per block (256 threads)
#define ITERS      2                   // row-groups per wave, loads all upfront
#define NBLOCKS    (RGROUPS / (WPB * ITERS))  // 1536

typedef __attribute__((ext_vector_type(4))) float    f32x4;
typedef __attribute__((ext_vector_type(8))) short    bf16x8;
typedef __attribute__((ext_vector_type(4))) uint32_t u32x4;

// round-half-up pack (used for W only; one-time cost, best accuracy)
__device__ __forceinline__ uint32_t pkbf16(float a, float b) {
    uint32_t ua = __float_as_uint(a);
    uint32_t ub = __float_as_uint(b);
    return ((ua + 0x8000u) >> 16) | ((ub + 0x8000u) & 0xffff0000u);
}
__device__ __forceinline__ bf16x8 pack8(f32x4 lo, f32x4 hi) {
    u32x4 u;
    u.x = pkbf16(lo[0], lo[1]);
    u.y = pkbf16(lo[2], lo[3]);
    u.z = pkbf16(hi[0], hi[1]);
    u.w = pkbf16(hi[2], hi[3]);
    return __builtin_bit_cast(bf16x8, u);
}

// truncating pack via one v_perm_b32: result = [hi16(b) : hi16(a)]
// sel bytes (LSB first): 6,7 (S0=a bytes 2,3), 2,3 (S1=b bytes 2,3)
__device__ __forceinline__ uint32_t pktr(float a, float b) {
    return __builtin_amdgcn_perm(__float_as_uint(a), __float_as_uint(b),
                                 0x03020706u);
}
__device__ __forceinline__ bf16x8 pack8t(f32x4 lo, f32x4 hi) {
    u32x4 u;
    u.x = pktr(lo[0], lo[1]);
    u.y = pktr(lo[2], lo[3]);
    u.z = pktr(hi[0], hi[1]);
    u.w = pktr(hi[2], hi[3]);
    return __builtin_bit_cast(bf16x8, u);
}

__global__ __launch_bounds__(256, 3) void ECGTokenizer_53420803228140_kernel(
    const float* __restrict__ ecg, const float* __restrict__ W,
    const float* __restrict__ b, float* __restrict__ out)
{
    // W fragments in LDS, fragment-major: slice (c*4+s), 64 lanes x 16B.
    // Wave read of one slice = contiguous 1 KB -> conflict-free.
    __shared__ short wlds[1024 * 8];   // 16 KiB

    const int lane = threadIdx.x & 63;
    const int wid  = threadIdx.x >> 6;
    const int l16  = lane & 15;   // ecg row within group / D col
    const int lg   = lane >> 4;   // k-subgroup (0..3)
    const int rg0  = (blockIdx.x * WPB + wid) * ITERS;

    // ---- issue ALL A loads first: 16 independent dwordx4, 16 KB in flight ----
    f32x4 a0[ITERS][4], a1[ITERS][4];
    #pragma unroll
    for (int it = 0; it < ITERS; ++it) {
        const float* arow = ecg + (size_t)(rg0 + it) * (16 * BEAT_LEN)
                          + (size_t)l16 * BEAT_LEN + 8 * lg;
        #pragma unroll
        for (int s = 0; s < 4; ++s) {
            a0[it][s] = *(const f32x4*)(arow + 32*s);
            a1[it][s] = *(const f32x4*)(arow + 32*s + 4);
        }
    }

    // ---- stage W (32 KB fp32 -> 16 KB bf16) into LDS under the A latency ----
    // chunk ch: slice = ch>>6 (= c*4+s), ln = ch&63; holds
    // W[16c + (ln&15)][32s + 8*(ln>>4) + e], e=0..7, packed bf16 (rounded).
    for (int ch = threadIdx.x; ch < 1024; ch += 256) {
        const int slice = ch >> 6, ln = ch & 63;
        const int c = slice >> 2, s = slice & 3;
        const int sl16 = ln & 15, slg = ln >> 4;
        const float* wp = W + (16*c + sl16)*BEAT_LEN + 32*s + 8*slg;
        f32x4 w0 = *(const f32x4*)(wp);
        f32x4 w1 = *(const f32x4*)(wp + 4);
        *(bf16x8*)&wlds[ch * 8] = pack8(w0, w1);
    }
    __syncthreads();

    // bias: lane's 4 acc entries are d = 16c + 4*lg + {0..3} -> contiguous
    f32x4 bvv[4];
    #pragma unroll
    for (int c = 0; c < 4; ++c) bvv[c] = *(const f32x4*)(b + 16*c + 4*lg);

    // ---- two straight-line compute+store passes, no loop-carried deps ----
    #pragma unroll
    for (int it = 0; it < ITERS; ++it) {
        bf16x8 af[4];
        #pragma unroll
        for (int s = 0; s < 4; ++s) af[s] = pack8t(a0[it][s], a1[it][s]);

        f32x4 acc[4];
        #pragma unroll
        for (int c = 0; c < 4; ++c) acc[c] = bvv[c];

        #pragma unroll
        for (int s = 0; s < 4; ++s) {
            #pragma unroll
            for (int c = 0; c < 4; ++c) {
                bf16x8 wf = *(const bf16x8*)&wlds[((c*4 + s)*64 + lane) * 8];
                acc[c] = __builtin_amdgcn_mfma_f32_16x16x32_bf16(
                             wf, af[s], acc[c], 0, 0, 0);
            }
        }

        // D: row (token dim) = 4*lg + reg, col (ecg row) = l16
        float* orow = out + ((size_t)(rg0 + it) * 16 + l16) * TOKEN_DIM + 4*lg;
        #pragma unroll
        for (int c = 0; c < 4; ++c) {
            __builtin_nontemporal_store(acc[c], (f32x4*)(orow + 16*c));
        }
    }

    // beat_intervals [128,128] = 128.0f, appended after X
    const int gtid = blockIdx.x * blockDim.x + threadIdx.x;
    if (gtid < N_BATCH * N_BEATS) {
        out[(size_t)M_ROWS * TOKEN_DIM + gtid] = 128.0f;
    }
}

extern "C" void kernel_launch(void* const* d_in, const int* in_sizes, int n_in,
                              void* d_out, int out_size, void* d_ws, size_t ws_size,
                              hipStream_t stream) {
    const float* ecg = (const float*)d_in[0];
    const float* W   = (const float*)d_in[1];
    const float* b   = (const float*)d_in[2];
    float* out       = (float*)d_out;
    hipLaunchKernelGGL(ECGTokenizer_53420803228140_kernel,
                       dim3(NBLOCKS), dim3(256), 0, stream,
                       ecg, W, b, out);
}